// Round 1
// baseline (1668.489 us; speedup 1.0000x reference)
//
#include <hip/hip_runtime.h>
#include <math.h>

#define H 64
#define NCONV 3
#define NGRAPHS 64
#define NCLASSES 10
#define TBL 4096

__device__ __forceinline__ float softplus_f(float x) {
    // jax.nn.softplus = logaddexp(x, 0) = max(x,0) + log1p(exp(-|x|))
    return fmaxf(x, 0.f) + log1pf(expf(-fabsf(x)));
}

// One block (64 threads) per table row. which = row / (TBL+1): 0=emb, 1..3=filt layer.
__global__ void build_tables(const float* __restrict__ W_emb1, const float* __restrict__ b_emb1,
                             const float* __restrict__ W_emb2, const float* __restrict__ b_emb2,
                             const float* __restrict__ fW1, const float* __restrict__ fb1,
                             const float* __restrict__ fW2, const float* __restrict__ fb2,
                             float* __restrict__ tabs /* [4][TBL+1][H] */)
{
    int row   = blockIdx.x;            // 0 .. 4*(TBL+1)-1
    int which = row / (TBL + 1);
    int t     = row % (TBL + 1);
    int j     = threadIdx.x;           // 0..63

    const float *W1, *b1, *W2, *b2;
    if (which == 0) { W1 = W_emb1; b1 = b_emb1; W2 = W_emb2; b2 = b_emb2; }
    else {
        int l = which - 1;
        W1 = fW1 + l * H * H; b1 = fb1 + l * H;
        W2 = fW2 + l * H * H; b2 = fb2 + l * H;
    }

    float dv = (float)t / (float)TBL;           // d in [0,1]
    // bf[j] = exp(-H * (d - mu_j)^2) * 0.5*(cos(pi*d)+1)
    float mu   = (float)j / (float)(H - 1);
    float diff = dv - mu;
    float cut  = 0.5f * (cosf(3.14159265358979323846f * dv) + 1.0f);
    float bfj  = expf(-(float)H * diff * diff) * cut;

    __shared__ float sh[H];
    sh[j] = bfj;
    __syncthreads();

    float acc = b1[j];
    #pragma unroll
    for (int i = 0; i < H; ++i) acc = fmaf(sh[i], W1[i * H + j], acc);
    float hj = softplus_f(acc);
    __syncthreads();
    sh[j] = hj;
    __syncthreads();

    float acc2 = b2[j];
    #pragma unroll
    for (int i = 0; i < H; ++i) acc2 = fmaf(sh[i], W2[i * H + j], acc2);

    tabs[(size_t)row * H + j] = acc2;
}

__device__ __forceinline__ float table_lerp(const float* __restrict__ tab, float dv, int lane) {
    dv = fminf(fmaxf(dv, 0.f), 1.f);
    float ft = dv * (float)TBL;
    int   t0 = (int)ft;
    if (t0 >= TBL) t0 = TBL - 1;
    float f  = ft - (float)t0;
    float v0 = tab[(size_t)t0 * H + lane];
    float v1 = tab[(size_t)(t0 + 1) * H + lane];
    return v0 + f * (v1 - v0);
}

// wave per edge: x[dst[e]][lane] += emb_tab(d[e])[lane]
__global__ void edge_emb_scatter(const float* __restrict__ d, const int* __restrict__ dst,
                                 const float* __restrict__ tab, float* __restrict__ x, int E)
{
    int e    = blockIdx.x * (blockDim.x >> 6) + (threadIdx.x >> 6);
    int lane = threadIdx.x & 63;
    if (e >= E) return;
    float v = table_lerp(tab, d[e], lane);
    atomicAdd(&x[(size_t)dst[e] * H + lane], v);
}

// wave per edge: agg[dst[e]][lane] += y[src[e]][lane] * filt_tab(d[e])[lane]
__global__ void edge_conv_scatter(const float* __restrict__ d, const int* __restrict__ src,
                                  const int* __restrict__ dst, const float* __restrict__ tab,
                                  const float* __restrict__ y, float* __restrict__ agg, int E)
{
    int e    = blockIdx.x * (blockDim.x >> 6) + (threadIdx.x >> 6);
    int lane = threadIdx.x & 63;
    if (e >= E) return;
    float filt = table_lerp(tab, d[e], lane);
    float v    = y[(size_t)src[e] * H + lane] * filt;
    atomicAdd(&agg[(size_t)dst[e] * H + lane], v);
}

// xout = (relu?)(xin @ W + b); wave per node, W staged in LDS
template <bool RELU>
__global__ void node_proj(const float* __restrict__ xin, const float* __restrict__ W,
                          const float* __restrict__ b, float* __restrict__ xout, int N)
{
    __shared__ float sW[H * H];
    __shared__ float sx[4][H];
    int tid = threadIdx.x;
    for (int i = tid; i < H * H; i += 256) sW[i] = W[i];

    int wave = tid >> 6, lane = tid & 63;
    int node = blockIdx.x * 4 + wave;
    float xi = (node < N) ? xin[(size_t)node * H + lane] : 0.f;
    sx[wave][lane] = xi;
    __syncthreads();

    if (node < N) {
        float acc = b[lane];
        #pragma unroll
        for (int i = 0; i < H; ++i) acc = fmaf(sx[wave][i], sW[i * H + lane], acc);
        if (RELU) acc = fmaxf(acc, 0.f);
        xout[(size_t)node * H + lane] = acc;
    }
}

__global__ void pool_kernel(const float* __restrict__ x, const int* __restrict__ gid,
                            float* __restrict__ pooled, float* __restrict__ counts, int N)
{
    int node = blockIdx.x * (blockDim.x >> 6) + (threadIdx.x >> 6);
    int lane = threadIdx.x & 63;
    if (node >= N) return;
    int g = gid[node];
    atomicAdd(&pooled[(size_t)g * H + lane], x[(size_t)node * H + lane]);
    if (lane == 0) atomicAdd(&counts[g], 1.0f);
}

// one block (64 threads) per graph: logits -> log_softmax
__global__ void head_kernel(const float* __restrict__ pooled, const float* __restrict__ counts,
                            const float* __restrict__ Wfc, const float* __restrict__ bfc,
                            float* __restrict__ out)
{
    int g = blockIdx.x;
    int c = threadIdx.x;
    __shared__ float logits[NCLASSES];
    float cnt = fmaxf(counts[g], 1.0f);
    if (c < NCLASSES) {
        float acc = bfc[c];
        #pragma unroll
        for (int i = 0; i < H; ++i)
            acc = fmaf(pooled[(size_t)g * H + i] / cnt, Wfc[i * NCLASSES + c], acc);
        logits[c] = acc;
    }
    __syncthreads();
    if (c < NCLASSES) {
        float m = -INFINITY;
        #pragma unroll
        for (int k = 0; k < NCLASSES; ++k) m = fmaxf(m, logits[k]);
        float s = 0.f;
        #pragma unroll
        for (int k = 0; k < NCLASSES; ++k) s += expf(logits[k] - m);
        out[g * NCLASSES + c] = logits[c] - m - logf(s);
    }
}

extern "C" void kernel_launch(void* const* d_in, const int* in_sizes, int n_in,
                              void* d_out, int out_size, void* d_ws, size_t ws_size,
                              hipStream_t stream)
{
    const float* d_d    = (const float*)d_in[0];
    const float* W_emb1 = (const float*)d_in[1];
    const float* b_emb1 = (const float*)d_in[2];
    const float* W_emb2 = (const float*)d_in[3];
    const float* b_emb2 = (const float*)d_in[4];
    const float* fW1    = (const float*)d_in[5];
    const float* fb1    = (const float*)d_in[6];
    const float* fW2    = (const float*)d_in[7];
    const float* fb2    = (const float*)d_in[8];
    const float* W_in   = (const float*)d_in[9];
    const float* b_in   = (const float*)d_in[10];
    const float* W_out  = (const float*)d_in[11];
    const float* b_out  = (const float*)d_in[12];
    const float* W_fc   = (const float*)d_in[13];
    const float* b_fc   = (const float*)d_in[14];
    const int*   src    = (const int*)d_in[15];
    const int*   dst    = (const int*)d_in[16];
    const int*   gid    = (const int*)d_in[17];

    const int E = in_sizes[0];
    const int N = in_sizes[17];

    float* out = (float*)d_out;

    // workspace layout
    float* x      = (float*)d_ws;                     // N*H
    float* y      = x + (size_t)N * H;                // N*H
    float* agg    = y + (size_t)N * H;                // N*H
    float* tabs   = agg + (size_t)N * H;              // 4*(TBL+1)*H
    float* pooled = tabs + (size_t)4 * (TBL + 1) * H; // NGRAPHS*H
    float* counts = pooled + (size_t)NGRAPHS * H;     // NGRAPHS

    const int edge_blocks = (E + 3) / 4;
    const int node_blocks = (N + 3) / 4;

    // 1. build the 4 MLP lookup tables
    build_tables<<<4 * (TBL + 1), 64, 0, stream>>>(W_emb1, b_emb1, W_emb2, b_emb2,
                                                   fW1, fb1, fW2, fb2, tabs);

    // 2. x = segment_sum(emb_mlp(bf), dst)
    hipMemsetAsync(x, 0, (size_t)N * H * sizeof(float), stream);
    edge_emb_scatter<<<edge_blocks, 256, 0, stream>>>(d_d, dst, tabs, x, E);

    // 3. conv layers
    for (int l = 0; l < NCONV; ++l) {
        node_proj<false><<<node_blocks, 256, 0, stream>>>(x, W_in + (size_t)l * H * H,
                                                          b_in + (size_t)l * H, y, N);
        hipMemsetAsync(agg, 0, (size_t)N * H * sizeof(float), stream);
        edge_conv_scatter<<<edge_blocks, 256, 0, stream>>>(d_d, src, dst,
                                                           tabs + (size_t)(1 + l) * (TBL + 1) * H,
                                                           y, agg, E);
        node_proj<true><<<node_blocks, 256, 0, stream>>>(agg, W_out + (size_t)l * H * H,
                                                         b_out + (size_t)l * H, x, N);
    }

    // 4. per-graph mean pooling
    hipMemsetAsync(pooled, 0, ((size_t)NGRAPHS * H + NGRAPHS) * sizeof(float), stream);
    pool_kernel<<<node_blocks, 256, 0, stream>>>(x, gid, pooled, counts, N);

    // 5. head: logits + log_softmax
    head_kernel<<<NGRAPHS, 64, 0, stream>>>(pooled, counts, W_fc, b_fc, out);
}

// Round 2
// 858.987 us; speedup vs baseline: 1.9424x; 1.9424x over previous
//
#include <hip/hip_runtime.h>
#include <math.h>

#define H 64
#define NCONV 3
#define NGRAPHS 64
#define NCLASSES 10
#define TBL 4096
#define SCAN_T 1024

__device__ __forceinline__ float softplus_f(float x) {
    return fmaxf(x, 0.f) + log1pf(expf(-fabsf(x)));
}

// One block (64 threads) per table row. which = row / (TBL+1): 0=emb, 1..3=filt layer.
__global__ void build_tables(const float* __restrict__ W_emb1, const float* __restrict__ b_emb1,
                             const float* __restrict__ W_emb2, const float* __restrict__ b_emb2,
                             const float* __restrict__ fW1, const float* __restrict__ fb1,
                             const float* __restrict__ fW2, const float* __restrict__ fb2,
                             float* __restrict__ tabs /* [4][TBL+1][H] */)
{
    int row   = blockIdx.x;
    int which = row / (TBL + 1);
    int t     = row % (TBL + 1);
    int j     = threadIdx.x;

    const float *W1, *b1, *W2, *b2;
    if (which == 0) { W1 = W_emb1; b1 = b_emb1; W2 = W_emb2; b2 = b_emb2; }
    else {
        int l = which - 1;
        W1 = fW1 + l * H * H; b1 = fb1 + l * H;
        W2 = fW2 + l * H * H; b2 = fb2 + l * H;
    }

    float dv = (float)t / (float)TBL;
    float mu   = (float)j / (float)(H - 1);
    float diff = dv - mu;
    float cut  = 0.5f * (cosf(3.14159265358979323846f * dv) + 1.0f);
    float bfj  = expf(-(float)H * diff * diff) * cut;

    __shared__ float sh[H];
    sh[j] = bfj;
    __syncthreads();

    float acc = b1[j];
    #pragma unroll
    for (int i = 0; i < H; ++i) acc = fmaf(sh[i], W1[i * H + j], acc);
    float hj = softplus_f(acc);
    __syncthreads();
    sh[j] = hj;
    __syncthreads();

    float acc2 = b2[j];
    #pragma unroll
    for (int i = 0; i < H; ++i) acc2 = fmaf(sh[i], W2[i * H + j], acc2);

    tabs[(size_t)row * H + j] = acc2;
}

__device__ __forceinline__ float table_lerp(const float* __restrict__ tab, float dv, int lane) {
    dv = fminf(fmaxf(dv, 0.f), 1.f);
    float ft = dv * (float)TBL;
    int   t0 = (int)ft;
    if (t0 >= TBL) t0 = TBL - 1;
    float f  = ft - (float)t0;
    float v0 = tab[(size_t)t0 * H + lane];
    float v1 = tab[(size_t)(t0 + 1) * H + lane];
    return v0 + f * (v1 - v0);
}

// ---------- CSR build (group edges by dst) ----------
__global__ void hist_kernel(const int* __restrict__ dst, int* __restrict__ cnt, int E) {
    int e = blockIdx.x * blockDim.x + threadIdx.x;
    if (e < E) atomicAdd(&cnt[dst[e]], 1);
}

// single-block exclusive scan of cnt[0..N) -> off[0..N]
__global__ void scan_kernel(const int* __restrict__ cnt, int* __restrict__ off, int N) {
    __shared__ int sums[SCAN_T];
    int t = threadIdx.x;
    int per = (N + SCAN_T - 1) / SCAN_T;
    int beg = t * per, end = min(beg + per, N);
    int s = 0;
    for (int i = beg; i < end; ++i) s += cnt[i];
    sums[t] = s;
    __syncthreads();
    for (int ofs = 1; ofs < SCAN_T; ofs <<= 1) {
        int v = (t >= ofs) ? sums[t - ofs] : 0;
        __syncthreads();
        sums[t] += v;
        __syncthreads();
    }
    int run = (t > 0) ? sums[t - 1] : 0;
    for (int i = beg; i < end; ++i) { off[i] = run; run += cnt[i]; }
    if (t == SCAN_T - 1) off[N] = run;
}

// pack (src, d) records sorted by dst
__global__ void scatter_kernel(const int* __restrict__ src, const int* __restrict__ dst,
                               const float* __restrict__ d, const int* __restrict__ off,
                               int* __restrict__ cursor, int* __restrict__ esrc,
                               float* __restrict__ ed, int E)
{
    int e = blockIdx.x * blockDim.x + threadIdx.x;
    if (e >= E) return;
    int v = dst[e];
    int pos = off[v] + atomicAdd(&cursor[v], 1);
    esrc[pos] = src[e];
    ed[pos]   = d[e];
}

// ---------- aggregation (gather form, no atomics) ----------
// x[n][lane] = sum over in-edges of emb_tab(d)
__global__ void emb_gather(const int* __restrict__ off, const float* __restrict__ ed,
                           const float* __restrict__ tab, float* __restrict__ x, int N)
{
    int node = blockIdx.x * (blockDim.x >> 6) + (threadIdx.x >> 6);
    int lane = threadIdx.x & 63;
    if (node >= N) return;
    int b = off[node], en = off[node + 1];
    float acc = 0.f;
    for (int p = b; p < en; ++p) acc += table_lerp(tab, ed[p], lane);
    x[(size_t)node * H + lane] = acc;
}

// xout[n] = relu( (sum_e filt(d_e) * y[src_e]) @ W + b )
__global__ void conv_fused(const int* __restrict__ off, const float* __restrict__ ed,
                           const int* __restrict__ esrc, const float* __restrict__ tab,
                           const float* __restrict__ y, const float* __restrict__ W,
                           const float* __restrict__ bvec, float* __restrict__ xout, int N)
{
    __shared__ float sW[H * H];
    __shared__ float sx[4][H];
    int tid = threadIdx.x;
    for (int i = tid; i < H * H; i += 256) sW[i] = W[i];

    int wave = tid >> 6, lane = tid & 63;
    int node = blockIdx.x * 4 + wave;
    float acc = 0.f;
    if (node < N) {
        int b = off[node], en = off[node + 1];
        for (int p = b; p < en; ++p) {
            float filt = table_lerp(tab, ed[p], lane);
            acc = fmaf(y[(size_t)esrc[p] * H + lane], filt, acc);
        }
    }
    sx[wave][lane] = acc;
    __syncthreads();

    if (node < N) {
        float o = bvec[lane];
        #pragma unroll
        for (int i = 0; i < H; ++i) o = fmaf(sx[wave][i], sW[i * H + lane], o);
        xout[(size_t)node * H + lane] = fmaxf(o, 0.f);
    }
}

// y = x @ W + b ; wave per node, W staged in LDS
__global__ void node_proj(const float* __restrict__ xin, const float* __restrict__ W,
                          const float* __restrict__ b, float* __restrict__ xout, int N)
{
    __shared__ float sW[H * H];
    __shared__ float sx[4][H];
    int tid = threadIdx.x;
    for (int i = tid; i < H * H; i += 256) sW[i] = W[i];

    int wave = tid >> 6, lane = tid & 63;
    int node = blockIdx.x * 4 + wave;
    float xi = (node < N) ? xin[(size_t)node * H + lane] : 0.f;
    sx[wave][lane] = xi;
    __syncthreads();

    if (node < N) {
        float acc = b[lane];
        #pragma unroll
        for (int i = 0; i < H; ++i) acc = fmaf(sx[wave][i], sW[i * H + lane], acc);
        xout[(size_t)node * H + lane] = acc;
    }
}

// per-graph mean pooling; gid sorted -> run-length accumulate, flush on change
__global__ void pool_kernel(const float* __restrict__ x, const int* __restrict__ gid,
                            float* __restrict__ pooled, float* __restrict__ counts, int N)
{
    int wavesPerBlock = blockDim.x >> 6;
    int wid  = blockIdx.x * wavesPerBlock + (threadIdx.x >> 6);
    int lane = threadIdx.x & 63;
    int totalWaves = gridDim.x * wavesPerBlock;
    int chunk = (N + totalWaves - 1) / totalWaves;
    int beg = wid * chunk, end = min(beg + chunk, N);
    if (beg >= end) return;

    float acc = 0.f;
    int cur = -1, cnt = 0;
    for (int n = beg; n < end; ++n) {
        int g = gid[n];
        if (g != cur) {
            if (cur >= 0) {
                atomicAdd(&pooled[(size_t)cur * H + lane], acc);
                if (lane == 0) atomicAdd(&counts[cur], (float)cnt);
            }
            cur = g; acc = 0.f; cnt = 0;
        }
        acc += x[(size_t)n * H + lane];
        cnt++;
    }
    atomicAdd(&pooled[(size_t)cur * H + lane], acc);
    if (lane == 0) atomicAdd(&counts[cur], (float)cnt);
}

// one block (64 threads) per graph: logits -> log_softmax
__global__ void head_kernel(const float* __restrict__ pooled, const float* __restrict__ counts,
                            const float* __restrict__ Wfc, const float* __restrict__ bfc,
                            float* __restrict__ out)
{
    int g = blockIdx.x;
    int c = threadIdx.x;
    __shared__ float logits[NCLASSES];
    float cnt = fmaxf(counts[g], 1.0f);
    if (c < NCLASSES) {
        float acc = bfc[c];
        #pragma unroll
        for (int i = 0; i < H; ++i)
            acc = fmaf(pooled[(size_t)g * H + i] / cnt, Wfc[i * NCLASSES + c], acc);
        logits[c] = acc;
    }
    __syncthreads();
    if (c < NCLASSES) {
        float m = -INFINITY;
        #pragma unroll
        for (int k = 0; k < NCLASSES; ++k) m = fmaxf(m, logits[k]);
        float s = 0.f;
        #pragma unroll
        for (int k = 0; k < NCLASSES; ++k) s += expf(logits[k] - m);
        out[g * NCLASSES + c] = logits[c] - m - logf(s);
    }
}

extern "C" void kernel_launch(void* const* d_in, const int* in_sizes, int n_in,
                              void* d_out, int out_size, void* d_ws, size_t ws_size,
                              hipStream_t stream)
{
    const float* d_d    = (const float*)d_in[0];
    const float* W_emb1 = (const float*)d_in[1];
    const float* b_emb1 = (const float*)d_in[2];
    const float* W_emb2 = (const float*)d_in[3];
    const float* b_emb2 = (const float*)d_in[4];
    const float* fW1    = (const float*)d_in[5];
    const float* fb1    = (const float*)d_in[6];
    const float* fW2    = (const float*)d_in[7];
    const float* fb2    = (const float*)d_in[8];
    const float* W_in   = (const float*)d_in[9];
    const float* b_in   = (const float*)d_in[10];
    const float* W_out  = (const float*)d_in[11];
    const float* b_out  = (const float*)d_in[12];
    const float* W_fc   = (const float*)d_in[13];
    const float* b_fc   = (const float*)d_in[14];
    const int*   src    = (const int*)d_in[15];
    const int*   dst    = (const int*)d_in[16];
    const int*   gid    = (const int*)d_in[17];

    const int E = in_sizes[0];
    const int N = in_sizes[17];

    float* out = (float*)d_out;

    // workspace layout
    char* base = (char*)d_ws;
    float* x      = (float*)base;                         base += (size_t)N * H * 4;
    float* y      = (float*)base;                         base += (size_t)N * H * 4;
    float* tabs   = (float*)base;                         base += (size_t)4 * (TBL + 1) * H * 4;
    float* pooled = (float*)base;                         base += (size_t)NGRAPHS * H * 4;
    float* counts = (float*)base;                         base += (size_t)NGRAPHS * 4;
    int*   cnt    = (int*)base;                           base += (size_t)N * 4;   // also reused as cursor
    int*   off    = (int*)base;                           base += (size_t)(N + 1) * 4;
    int*   esrc   = (int*)base;                           base += (size_t)E * 4;
    float* ed     = (float*)base;                         base += (size_t)E * 4;

    const int edge_tblocks = (E + 255) / 256;
    const int node_blocks4 = (N + 3) / 4;

    // 1. MLP lookup tables
    build_tables<<<4 * (TBL + 1), 64, 0, stream>>>(W_emb1, b_emb1, W_emb2, b_emb2,
                                                   fW1, fb1, fW2, fb2, tabs);

    // 2. CSR build: group edges by dst
    hipMemsetAsync(cnt, 0, (size_t)N * 4, stream);
    hist_kernel<<<edge_tblocks, 256, 0, stream>>>(dst, cnt, E);
    scan_kernel<<<1, SCAN_T, 0, stream>>>(cnt, off, N);
    hipMemsetAsync(cnt, 0, (size_t)N * 4, stream);
    scatter_kernel<<<edge_tblocks, 256, 0, stream>>>(src, dst, d_d, off, cnt, esrc, ed, E);

    // 3. embedding: x[n] = sum_in-edges emb_tab(d)
    emb_gather<<<node_blocks4, 256, 0, stream>>>(off, ed, tabs, x, N);

    // 4. conv layers: y = x@W_in+b ; x = relu((sum filt*y[src]) @ W_out + b)
    for (int l = 0; l < NCONV; ++l) {
        node_proj<<<node_blocks4, 256, 0, stream>>>(x, W_in + (size_t)l * H * H,
                                                    b_in + (size_t)l * H, y, N);
        conv_fused<<<node_blocks4, 256, 0, stream>>>(off, ed, esrc,
                                                     tabs + (size_t)(1 + l) * (TBL + 1) * H,
                                                     y, W_out + (size_t)l * H * H,
                                                     b_out + (size_t)l * H, x, N);
    }

    // 5. per-graph mean pooling (sorted gid -> run-length flush)
    hipMemsetAsync(pooled, 0, ((size_t)NGRAPHS * H + NGRAPHS) * 4, stream);
    pool_kernel<<<128, 256, 0, stream>>>(x, gid, pooled, counts, N);

    // 6. head
    head_kernel<<<NGRAPHS, 64, 0, stream>>>(pooled, counts, W_fc, b_fc, out);
}